// Round 14
// baseline (122.106 us; speedup 1.0000x reference)
//
#include <hip/hip_runtime.h>
#include <math.h>

#define NN 100000
#define NE 3200000
#define INC 128
#define HID 16
#define OC 40

#define NBK 391       // buckets of 256 dst-nodes: ceil(100000/256)
#define CAP 8960      // mean 8184 + ~8.5 sigma
#define CSTRIDE 16    // one 64B line per cursor
#define EB 8192       // edges per partition block
#define PBLK 391      // ceil(NE/EB)

__device__ __forceinline__ unsigned bf16r(float f) {  // RNE fp32->bf16 (as u16)
    unsigned u = __float_as_uint(f);
    return (u + 0x7FFFu + ((u >> 16) & 1u)) >> 16;
}
__device__ __forceinline__ unsigned packbf(float a, float b) {
    return bf16r(a) | (bf16r(b) << 16);
}
__device__ __forceinline__ float bflo(unsigned u) { return __uint_as_float(u << 16); }
__device__ __forceinline__ float bfhi(unsigned u) { return __uint_as_float(u & 0xFFFF0000u); }

__global__ void k_zero_i(int* __restrict__ p, int n) {
    int i = blockIdx.x * blockDim.x + threadIdx.x;
    if (i < n) p[i] = 0;
}

// Two-level partition, single global pass, 16 edges/thread in registers.
// Packed word = (dst&255)<<17 | src   (src < 2^17).
__global__ __launch_bounds__(512) void k_part(const int* __restrict__ src,
                                              const int* __restrict__ dst,
                                              int* __restrict__ cursor,
                                              int* __restrict__ bin) {
    __shared__ int hist[512];
    __shared__ int pref[512];     // exclusive local start per bucket
    __shared__ int lcur[512];
    __shared__ int gbase[512];
    __shared__ unsigned sorted[EB];         // 32KB
    __shared__ unsigned short sortedb[EB];  // 16KB
    __shared__ int wsum[8], wbase[8];
    __shared__ int tot_s;
    int t = threadIdx.x;
    int lane = t & 63, wid = t >> 6;
    int e0 = blockIdx.x * EB;
    int cnt = min(EB, NE - e0);
    hist[t] = 0;
    __syncthreads();
    // single read pass: keep edges in registers (fully unrolled -> static idx)
    unsigned wreg[16];
    int breg[16];
#pragma unroll
    for (int k = 0; k < 16; ++k) {
        int i = t + k * 512;
        breg[k] = -1;
        if (i < cnt) {
            unsigned d = (unsigned)dst[e0 + i];
            unsigned s = (unsigned)src[e0 + i];
            if (d < NN && s < NN) {
                breg[k] = (int)(d >> 8);
                wreg[k] = ((d & 255u) << 17) | s;
                atomicAdd(&hist[breg[k]], 1);
            }
        }
    }
    __syncthreads();
    // shfl-based scan of hist[512]
    int v = hist[t];
    int sv = v;
#pragma unroll
    for (int d = 1; d < 64; d <<= 1) {
        int up = __shfl_up(sv, d);
        if (lane >= d) sv += up;
    }
    if (lane == 63) wsum[wid] = sv;
    __syncthreads();
    if (t < 8) {
        int acc = 0;
        for (int i = 0; i < t; ++i) acc += wsum[i];
        wbase[t] = acc;
    }
    __syncthreads();
    int incl = sv + wbase[wid];
    int excl = incl - v;
    pref[t] = excl;
    lcur[t] = 0;
    if (t == 511) tot_s = incl;
    if (t < NBK) gbase[t] = atomicAdd(&cursor[t * CSTRIDE], v);
    __syncthreads();
    // scatter from registers into LDS
#pragma unroll
    for (int k = 0; k < 16; ++k) {
        if (breg[k] >= 0) {
            int b = breg[k];
            int p = atomicAdd(&lcur[b], 1);
            int idx = pref[b] + p;
            sorted[idx] = wreg[k];
            sortedb[idx] = (unsigned short)b;
        }
    }
    __syncthreads();
    int tot = tot_s;
    for (int i = t; i < tot; i += 512) {
        int b = sortedb[i];
        int gp = gbase[b] + (i - pref[b]);
        if (gp < CAP) bin[b * CAP + gp] = (int)sorted[i];
    }
}

// per-bucket counting sort by local dst (in place); single bin read held in
// registers across histogram->scatter; shfl scan; emits offend/dis
__global__ __launch_bounds__(512) void k_bsort(int* __restrict__ bin,
                                               const int* __restrict__ cursor,
                                               int2* __restrict__ offend,
                                               float* __restrict__ dis) {
    __shared__ int hist[256];
    __shared__ int pref[256];   // inclusive
    __shared__ int lcur[256];
    __shared__ int sorted[CAP];  // 35.8KB
    __shared__ int wsum[4], wbase[4];
    int b = blockIdx.x, t = threadIdx.x;
    int cnt = cursor[b * CSTRIDE];
    if (cnt > CAP) cnt = CAP;
    int base = b * CAP;
    if (t < 256) hist[t] = 0;
    __syncthreads();
    unsigned wreg[18];  // 18*512 = 9216 >= CAP
#pragma unroll
    for (int k = 0; k < 18; ++k) {
        int i = t + k * 512;
        if (i < cnt) {
            unsigned w = (unsigned)bin[base + i];
            wreg[k] = w;
            atomicAdd(&hist[w >> 17], 1);
        }
    }
    __syncthreads();
    int v = 0, sv = 0;
    if (t < 256) {
        v = hist[t];
        sv = v;
        int lane = t & 63;
#pragma unroll
        for (int d = 1; d < 64; d <<= 1) {
            int up = __shfl_up(sv, d);
            if (lane >= d) sv += up;
        }
        if (lane == 63) wsum[t >> 6] = sv;
    }
    __syncthreads();
    if (t < 4) {
        int acc = 0;
        for (int i = 0; i < t; ++i) acc += wsum[i];
        wbase[t] = acc;
    }
    __syncthreads();
    if (t < 256) {
        int incl = sv + wbase[t >> 6];
        pref[t] = incl;
        lcur[t] = incl - v;
    }
    __syncthreads();
#pragma unroll
    for (int k = 0; k < 18; ++k) {
        int i = t + k * 512;
        if (i < cnt) {
            unsigned w = wreg[k];
            int p = atomicAdd(&lcur[w >> 17], 1);
            sorted[p] = (int)(w & 0x1FFFF);
        }
    }
    __syncthreads();
    for (int i = t; i < cnt; i += 512) bin[base + i] = sorted[i];
    if (t < 256) {
        int node = (b << 8) + t;
        if (node < NN) {
            int2 oe; oe.x = base + pref[t] - hist[t]; oe.y = base + pref[t];
            offend[node] = oe;
            dis[node]  = rsqrtf((float)(hist[t] + 1));  // +1 self-loop
        }
    }
}

// g1[bf16] = dis[i] * (x @ W1)[i] ; float4 global loads
__global__ __launch_bounds__(256) void k_gemm1(const float* __restrict__ x,
                                               const float* __restrict__ W1,
                                               const float* __restrict__ dis,
                                               unsigned* __restrict__ g1) {
    __shared__ float xs[16][132];   // pad 4: keeps rows 16B-aligned
    __shared__ float ws[INC][HID];
    __shared__ float accs[16][17];
    int t = threadIdx.x;
    int rowbase = blockIdx.x * 16;  // NN/16 = 6250 exact
    const float4* x4 = (const float4*)(x + (size_t)rowbase * INC);  // 512 float4
#pragma unroll
    for (int i = 0; i < 2; ++i) {
        int idx = t + i * 256;
        float4 vv = x4[idx];
        *(float4*)&xs[idx >> 5][(idx & 31) * 4] = vv;
    }
    const float4* w4 = (const float4*)W1;  // 512 float4
#pragma unroll
    for (int i = 0; i < 2; ++i) {
        int idx = t + i * 256;
        float4 vv = w4[idx];
        *(float4*)&ws[idx >> 2][(idx & 3) * 4] = vv;
    }
    __syncthreads();
    int r = t >> 4, c = t & 15;
    float acc = 0.f;
#pragma unroll
    for (int k = 0; k < INC; ++k) acc += xs[r][k] * ws[k][c];
    accs[r][c] = dis[rowbase + r] * acc;
    __syncthreads();
    if (t < 128) {
        int row = t >> 3, p = t & 7;
        g1[(rowbase + row) * 8 + p] = packbf(accs[row][2 * p], accs[row][2 * p + 1]);
    }
}

#define UNPACK4(u, f) \
    f[0] = bflo(u.x); f[1] = bfhi(u.x); f[2] = bflo(u.y); f[3] = bfhi(u.y);
#define ACC4(u)                         \
    { float f[4]; UNPACK4(u, f)         \
      a[0] += f[0]; a[1] += f[1]; a[2] += f[2]; a[3] += f[3]; }

// Gather core: 16 lanes/node = 4 channel-groups (uint2) x 4 edge-strides.
// 8 independent loads per round = full mean segment (deg 32 / 4 strides).
__device__ __forceinline__ void gather_core(const unsigned* __restrict__ gin,
                                            const int* __restrict__ bin,
                                            int node, int c4, int es,
                                            int beg, int end, float di,
                                            float a[4]) {
    const uint2* gv = (const uint2*)gin;
    if (es == 0) {
        uint2 u = gv[node * 4 + c4];  // self contribution once
        UNPACK4(u, a)
    } else {
        a[0] = a[1] = a[2] = a[3] = 0.f;
    }
    int j = beg + es;
    for (; j + 28 < end; j += 32) {  // 8 independent loads in flight
        int s0 = bin[j],      s1 = bin[j + 4],  s2 = bin[j + 8],  s3 = bin[j + 12];
        int s4 = bin[j + 16], s5 = bin[j + 20], s6 = bin[j + 24], s7 = bin[j + 28];
        uint2 u0 = gv[s0 * 4 + c4];
        uint2 u1 = gv[s1 * 4 + c4];
        uint2 u2 = gv[s2 * 4 + c4];
        uint2 u3 = gv[s3 * 4 + c4];
        uint2 u4 = gv[s4 * 4 + c4];
        uint2 u5 = gv[s5 * 4 + c4];
        uint2 u6 = gv[s6 * 4 + c4];
        uint2 u7 = gv[s7 * 4 + c4];
        ACC4(u0) ACC4(u1) ACC4(u2) ACC4(u3)
        ACC4(u4) ACC4(u5) ACC4(u6) ACC4(u7)
    }
    for (; j + 12 < end; j += 16) {  // 4-deep middle
        int s0 = bin[j], s1 = bin[j + 4], s2 = bin[j + 8], s3 = bin[j + 12];
        uint2 u0 = gv[s0 * 4 + c4];
        uint2 u1 = gv[s1 * 4 + c4];
        uint2 u2 = gv[s2 * 4 + c4];
        uint2 u3 = gv[s3 * 4 + c4];
        ACC4(u0) ACC4(u1) ACC4(u2) ACC4(u3)
    }
    for (; j < end; j += 4) {
        uint2 uu = gv[bin[j] * 4 + c4];
        ACC4(uu)
    }
#pragma unroll
    for (int k = 0; k < 4; ++k) {
        a[k] += __shfl_xor(a[k], 4);   // combine es pairs
        a[k] += __shfl_xor(a[k], 8);   // combine es quads
        a[k] *= di;
    }
}

// layer-1 gather: g2[bf16] = relu(conv + b1) * di ; 16 nodes per 256-block
__global__ __launch_bounds__(256) void k_gather1(const unsigned* __restrict__ gin,
                                                 const float* __restrict__ dis,
                                                 const int2* __restrict__ offend,
                                                 const int* __restrict__ bin,
                                                 const float* __restrict__ bias,
                                                 unsigned* __restrict__ outbf) {
    int t = threadIdx.x;
    int node = blockIdx.x * 16 + (t >> 4);
    if (node >= NN) return;
    int lane4 = t & 15;
    int c4 = lane4 & 3, es = lane4 >> 2;
    float di = dis[node];
    int2 oe = offend[node];
    float a[4];
    gather_core(gin, bin, node, c4, es, oe.x, oe.y, di, a);
    if (es == 0) {
#pragma unroll
        for (int k = 0; k < 4; ++k)
            a[k] = fmaxf(a[k] + bias[c4 * 4 + k], 0.f) * di;
        uint2 o; o.x = packbf(a[0], a[1]); o.y = packbf(a[2], a[3]);
        ((uint2*)outbf)[node * 4 + c4] = o;
    }
}

// layer-2 gather fused with W2 GEMV + bias + log_softmax.
// Phase 1: gather_core -> LDS transpose. Phase 2: 8 lanes/node x 5 logits.
__global__ __launch_bounds__(256) void k_gather2(const unsigned* __restrict__ gin,
                                                 const float* __restrict__ dis,
                                                 const int2* __restrict__ offend,
                                                 const int* __restrict__ bin,
                                                 const float* __restrict__ W2,
                                                 const float* __restrict__ b2,
                                                 float* __restrict__ out) {
    __shared__ float accs[16][HID + 1];
    __shared__ float w2s[HID * OC];
    __shared__ float b2s[OC];
    int t = threadIdx.x;
    for (int i = t; i < HID * OC; i += 256) w2s[i] = W2[i];
    if (t < OC) b2s[t] = b2[t];
    int nl = t >> 4;
    int node = blockIdx.x * 16 + nl;  // NN = 6250*16 exact
    int lane4 = t & 15;
    int c4 = lane4 & 3, es = lane4 >> 2;
    if (node < NN) {
        float di = dis[node];
        int2 oe = offend[node];
        float a[4];
        gather_core(gin, bin, node, c4, es, oe.x, oe.y, di, a);
        if (es == 0) {
#pragma unroll
            for (int k = 0; k < 4; ++k) accs[nl][c4 * 4 + k] = a[k];
        }
    }
    __syncthreads();
    if (node >= NN || lane4 >= 8) return;
    float a[HID];
#pragma unroll
    for (int k = 0; k < HID; ++k) a[k] = accs[nl][k];
    float z[5];
#pragma unroll
    for (int j = 0; j < 5; ++j) {
        int c = lane4 * 5 + j;
        float zz = b2s[c];
#pragma unroll
        for (int k = 0; k < HID; ++k) zz += a[k] * w2s[k * OC + c];
        z[j] = zz;
    }
    float m = z[0];
#pragma unroll
    for (int j = 1; j < 5; ++j) m = fmaxf(m, z[j]);
    m = fmaxf(m, __shfl_xor(m, 1));
    m = fmaxf(m, __shfl_xor(m, 2));
    m = fmaxf(m, __shfl_xor(m, 4));
    float s = 0.f;
#pragma unroll
    for (int j = 0; j < 5; ++j) s += expf(z[j] - m);
    s += __shfl_xor(s, 1);
    s += __shfl_xor(s, 2);
    s += __shfl_xor(s, 4);
    float lse = m + logf(s);
    float* op = out + (size_t)node * OC + lane4 * 5;
#pragma unroll
    for (int j = 0; j < 5; ++j) op[j] = z[j] - lse;
}

extern "C" void kernel_launch(void* const* d_in, const int* in_sizes, int n_in,
                              void* d_out, int out_size, void* d_ws, size_t ws_size,
                              hipStream_t stream) {
    const float* x  = (const float*)d_in[0];
    const int*   ei = (const int*)d_in[1];
    const float* W1 = (const float*)d_in[2];
    const float* b1 = (const float*)d_in[3];
    const float* W2 = (const float*)d_in[4];
    const float* b2 = (const float*)d_in[5];
    float* out = (float*)d_out;

    const int* src = ei;       // edge_index[0]
    const int* dst = ei + NE;  // edge_index[1]

    char* ws = (char*)d_ws;
    size_t o = 0;
    int*      cursor = (int*)(ws + o);      o += (size_t)NBK * CSTRIDE * 4;  // 25KB
    float*    dis    = (float*)(ws + o);    o += (size_t)NN * 4;             // 400KB
    int2*     offend = (int2*)(ws + o);     o += (size_t)NN * 8;             // 800KB
    int*      bin    = (int*)(ws + o);      o += (size_t)NBK * CAP * 4;      // 14.0MB
    unsigned* gbf1   = (unsigned*)(ws + o); o += (size_t)NN * 8 * 4;         // 3.2MB
    unsigned* gbf2   = (unsigned*)(ws + o); o += (size_t)NN * 8 * 4;         // 3.2MB

    dim3 B(256);
    int gC = (NBK * CSTRIDE + 255) / 256;
    int gG = (NN + 15) / 16;  // 6250 blocks

    k_zero_i<<<gC, B, 0, stream>>>(cursor, NBK * CSTRIDE);
    k_part<<<PBLK, 512, 0, stream>>>(src, dst, cursor, bin);
    k_bsort<<<NBK, 512, 0, stream>>>(bin, cursor, offend, dis);
    k_gemm1<<<NN / 16, B, 0, stream>>>(x, W1, dis, gbf1);
    k_gather1<<<gG, B, 0, stream>>>(gbf1, dis, offend, bin, b1, gbf2);
    k_gather2<<<gG, B, 0, stream>>>(gbf2, dis, offend, bin, W2, b2, out);
}

// Round 15
// 119.256 us; speedup vs baseline: 1.0239x; 1.0239x over previous
//
#include <hip/hip_runtime.h>
#include <math.h>

#define NN 100000
#define NE 3200000
#define INC 128
#define HID 16
#define OC 40

#define NBK 391       // buckets of 256 dst-nodes: ceil(100000/256)
#define CAP 8960      // mean 8184 + ~8.5 sigma
#define CSTRIDE 16    // one 64B line per cursor
#define EB 8192       // edges per partition block
#define PBLK 391      // ceil(NE/EB)
#define SPANCAP 2048  // LDS-staged edge span per 16-node gather block (+68 sigma)

__device__ __forceinline__ unsigned bf16r(float f) {  // RNE fp32->bf16 (as u16)
    unsigned u = __float_as_uint(f);
    return (u + 0x7FFFu + ((u >> 16) & 1u)) >> 16;
}
__device__ __forceinline__ unsigned packbf(float a, float b) {
    return bf16r(a) | (bf16r(b) << 16);
}
__device__ __forceinline__ float bflo(unsigned u) { return __uint_as_float(u << 16); }
__device__ __forceinline__ float bfhi(unsigned u) { return __uint_as_float(u & 0xFFFF0000u); }

__global__ void k_zero_i(int* __restrict__ p, int n) {
    int i = blockIdx.x * blockDim.x + threadIdx.x;
    if (i < n) p[i] = 0;
}

// Two-level partition, single global pass, 16 edges/thread in registers.
// Packed word = (dst&255)<<17 | src   (src < 2^17).
__global__ __launch_bounds__(512) void k_part(const int* __restrict__ src,
                                              const int* __restrict__ dst,
                                              int* __restrict__ cursor,
                                              int* __restrict__ bin) {
    __shared__ int hist[512];
    __shared__ int pref[512];     // exclusive local start per bucket
    __shared__ int lcur[512];
    __shared__ int gbase[512];
    __shared__ unsigned sorted[EB];         // 32KB
    __shared__ unsigned short sortedb[EB];  // 16KB
    __shared__ int wsum[8], wbase[8];
    __shared__ int tot_s;
    int t = threadIdx.x;
    int lane = t & 63, wid = t >> 6;
    int e0 = blockIdx.x * EB;
    int cnt = min(EB, NE - e0);
    hist[t] = 0;
    __syncthreads();
    // single read pass: keep edges in registers (fully unrolled -> static idx)
    unsigned wreg[16];
    int breg[16];
#pragma unroll
    for (int k = 0; k < 16; ++k) {
        int i = t + k * 512;
        breg[k] = -1;
        if (i < cnt) {
            unsigned d = (unsigned)dst[e0 + i];
            unsigned s = (unsigned)src[e0 + i];
            if (d < NN && s < NN) {
                breg[k] = (int)(d >> 8);
                wreg[k] = ((d & 255u) << 17) | s;
                atomicAdd(&hist[breg[k]], 1);
            }
        }
    }
    __syncthreads();
    // shfl-based scan of hist[512]
    int v = hist[t];
    int sv = v;
#pragma unroll
    for (int d = 1; d < 64; d <<= 1) {
        int up = __shfl_up(sv, d);
        if (lane >= d) sv += up;
    }
    if (lane == 63) wsum[wid] = sv;
    __syncthreads();
    if (t < 8) {
        int acc = 0;
        for (int i = 0; i < t; ++i) acc += wsum[i];
        wbase[t] = acc;
    }
    __syncthreads();
    int incl = sv + wbase[wid];
    int excl = incl - v;
    pref[t] = excl;
    lcur[t] = 0;
    if (t == 511) tot_s = incl;
    if (t < NBK) gbase[t] = atomicAdd(&cursor[t * CSTRIDE], v);
    __syncthreads();
    // scatter from registers into LDS
#pragma unroll
    for (int k = 0; k < 16; ++k) {
        if (breg[k] >= 0) {
            int b = breg[k];
            int p = atomicAdd(&lcur[b], 1);
            int idx = pref[b] + p;
            sorted[idx] = wreg[k];
            sortedb[idx] = (unsigned short)b;
        }
    }
    __syncthreads();
    int tot = tot_s;
    for (int i = t; i < tot; i += 512) {
        int b = sortedb[i];
        int gp = gbase[b] + (i - pref[b]);
        if (gp < CAP) bin[b * CAP + gp] = (int)sorted[i];
    }
}

// per-bucket counting sort by local dst (in place); single bin read held in
// registers across histogram->scatter; shfl scan; emits offend/dis
__global__ __launch_bounds__(512) void k_bsort(int* __restrict__ bin,
                                               const int* __restrict__ cursor,
                                               int2* __restrict__ offend,
                                               float* __restrict__ dis) {
    __shared__ int hist[256];
    __shared__ int pref[256];   // inclusive
    __shared__ int lcur[256];
    __shared__ int sorted[CAP];  // 35.8KB
    __shared__ int wsum[4], wbase[4];
    int b = blockIdx.x, t = threadIdx.x;
    int cnt = cursor[b * CSTRIDE];
    if (cnt > CAP) cnt = CAP;
    int base = b * CAP;
    if (t < 256) hist[t] = 0;
    __syncthreads();
    unsigned wreg[18];  // 18*512 = 9216 >= CAP
#pragma unroll
    for (int k = 0; k < 18; ++k) {
        int i = t + k * 512;
        if (i < cnt) {
            unsigned w = (unsigned)bin[base + i];
            wreg[k] = w;
            atomicAdd(&hist[w >> 17], 1);
        }
    }
    __syncthreads();
    int v = 0, sv = 0;
    if (t < 256) {
        v = hist[t];
        sv = v;
        int lane = t & 63;
#pragma unroll
        for (int d = 1; d < 64; d <<= 1) {
            int up = __shfl_up(sv, d);
            if (lane >= d) sv += up;
        }
        if (lane == 63) wsum[t >> 6] = sv;
    }
    __syncthreads();
    if (t < 4) {
        int acc = 0;
        for (int i = 0; i < t; ++i) acc += wsum[i];
        wbase[t] = acc;
    }
    __syncthreads();
    if (t < 256) {
        int incl = sv + wbase[t >> 6];
        pref[t] = incl;
        lcur[t] = incl - v;
    }
    __syncthreads();
#pragma unroll
    for (int k = 0; k < 18; ++k) {
        int i = t + k * 512;
        if (i < cnt) {
            unsigned w = wreg[k];
            int p = atomicAdd(&lcur[w >> 17], 1);
            sorted[p] = (int)(w & 0x1FFFF);
        }
    }
    __syncthreads();
    for (int i = t; i < cnt; i += 512) bin[base + i] = sorted[i];
    if (t < 256) {
        int node = (b << 8) + t;
        if (node < NN) {
            int2 oe; oe.x = base + pref[t] - hist[t]; oe.y = base + pref[t];
            offend[node] = oe;
            dis[node]  = rsqrtf((float)(hist[t] + 1));  // +1 self-loop
        }
    }
}

// g1[bf16] = dis[i] * (x @ W1)[i] ; float4 global loads
__global__ __launch_bounds__(256) void k_gemm1(const float* __restrict__ x,
                                               const float* __restrict__ W1,
                                               const float* __restrict__ dis,
                                               unsigned* __restrict__ g1) {
    __shared__ float xs[16][132];   // pad 4: keeps rows 16B-aligned
    __shared__ float ws[INC][HID];
    __shared__ float accs[16][17];
    int t = threadIdx.x;
    int rowbase = blockIdx.x * 16;  // NN/16 = 6250 exact
    const float4* x4 = (const float4*)(x + (size_t)rowbase * INC);  // 512 float4
#pragma unroll
    for (int i = 0; i < 2; ++i) {
        int idx = t + i * 256;
        float4 vv = x4[idx];
        *(float4*)&xs[idx >> 5][(idx & 31) * 4] = vv;
    }
    const float4* w4 = (const float4*)W1;  // 512 float4
#pragma unroll
    for (int i = 0; i < 2; ++i) {
        int idx = t + i * 256;
        float4 vv = w4[idx];
        *(float4*)&ws[idx >> 2][(idx & 3) * 4] = vv;
    }
    __syncthreads();
    int r = t >> 4, c = t & 15;
    float acc = 0.f;
#pragma unroll
    for (int k = 0; k < INC; ++k) acc += xs[r][k] * ws[k][c];
    accs[r][c] = dis[rowbase + r] * acc;
    __syncthreads();
    if (t < 128) {
        int row = t >> 3, p = t & 7;
        g1[(rowbase + row) * 8 + p] = packbf(accs[row][2 * p], accs[row][2 * p + 1]);
    }
}

#define UNPACK4(u, f) \
    f[0] = bflo(u.x); f[1] = bfhi(u.x); f[2] = bflo(u.y); f[3] = bfhi(u.y);
#define ACC4(u)                         \
    { float f[4]; UNPACK4(u, f)         \
      a[0] += f[0]; a[1] += f[1]; a[2] += f[2]; a[3] += f[3]; }

// Gather walk: 16 lanes/node = 4 channel-groups (uint2) x 4 edge-strides.
// idx points at the edge list (LDS-staged on the hot path; global fallback —
// forceinline + per-call-site addrspace inference keeps LDS path on ds_read).
__device__ __forceinline__ void gather_walk(const unsigned* __restrict__ gin,
                                            const int* idx,
                                            int node, int c4, int es,
                                            int beg, int end, float di,
                                            float a[4]) {
    const uint2* gv = (const uint2*)gin;
    if (es == 0) {
        uint2 u = gv[node * 4 + c4];  // self contribution once
        UNPACK4(u, a)
    } else {
        a[0] = a[1] = a[2] = a[3] = 0.f;
    }
    int j = beg + es;
    for (; j + 28 < end; j += 32) {  // 8 independent loads in flight
        int s0 = idx[j],      s1 = idx[j + 4],  s2 = idx[j + 8],  s3 = idx[j + 12];
        int s4 = idx[j + 16], s5 = idx[j + 20], s6 = idx[j + 24], s7 = idx[j + 28];
        uint2 u0 = gv[s0 * 4 + c4];
        uint2 u1 = gv[s1 * 4 + c4];
        uint2 u2 = gv[s2 * 4 + c4];
        uint2 u3 = gv[s3 * 4 + c4];
        uint2 u4 = gv[s4 * 4 + c4];
        uint2 u5 = gv[s5 * 4 + c4];
        uint2 u6 = gv[s6 * 4 + c4];
        uint2 u7 = gv[s7 * 4 + c4];
        ACC4(u0) ACC4(u1) ACC4(u2) ACC4(u3)
        ACC4(u4) ACC4(u5) ACC4(u6) ACC4(u7)
    }
    for (; j + 12 < end; j += 16) {  // 4-deep middle
        int s0 = idx[j], s1 = idx[j + 4], s2 = idx[j + 8], s3 = idx[j + 12];
        uint2 u0 = gv[s0 * 4 + c4];
        uint2 u1 = gv[s1 * 4 + c4];
        uint2 u2 = gv[s2 * 4 + c4];
        uint2 u3 = gv[s3 * 4 + c4];
        ACC4(u0) ACC4(u1) ACC4(u2) ACC4(u3)
    }
    for (; j < end; j += 4) {
        uint2 uu = gv[idx[j] * 4 + c4];
        ACC4(uu)
    }
#pragma unroll
    for (int k = 0; k < 4; ++k) {
        a[k] += __shfl_xor(a[k], 4);   // combine es pairs
        a[k] += __shfl_xor(a[k], 8);   // combine es quads
        a[k] *= di;
    }
}

// layer-1 gather: g2[bf16] = relu(conv + b1) * di ; 16 nodes per 256-block.
// Block's 16 node segments are one contiguous bin span -> stage in LDS.
__global__ __launch_bounds__(256) void k_gather1(const unsigned* __restrict__ gin,
                                                 const float* __restrict__ dis,
                                                 const int2* __restrict__ offend,
                                                 const int* __restrict__ bin,
                                                 const float* __restrict__ bias,
                                                 unsigned* __restrict__ outbf) {
    __shared__ int lbin[SPANCAP];
    int t = threadIdx.x;
    int node0 = blockIdx.x * 16;
    int base0 = offend[node0].x;
    int span = offend[node0 + 15].y - base0;
    if (span <= SPANCAP) {
        for (int i = t; i < span; i += 256) lbin[i] = bin[base0 + i];
    }
    __syncthreads();
    int node = node0 + (t >> 4);   // NN = 6250*16 exact
    int lane4 = t & 15;
    int c4 = lane4 & 3, es = lane4 >> 2;
    float di = dis[node];
    int2 oe = offend[node];
    float a[4];
    if (span <= SPANCAP)
        gather_walk(gin, lbin, node, c4, es, oe.x - base0, oe.y - base0, di, a);
    else
        gather_walk(gin, bin, node, c4, es, oe.x, oe.y, di, a);
    if (es == 0) {
#pragma unroll
        for (int k = 0; k < 4; ++k)
            a[k] = fmaxf(a[k] + bias[c4 * 4 + k], 0.f) * di;
        uint2 o; o.x = packbf(a[0], a[1]); o.y = packbf(a[2], a[3]);
        ((uint2*)outbf)[node * 4 + c4] = o;
    }
}

// layer-2 gather fused with W2 GEMV + bias + log_softmax; LDS-staged indices.
__global__ __launch_bounds__(256) void k_gather2(const unsigned* __restrict__ gin,
                                                 const float* __restrict__ dis,
                                                 const int2* __restrict__ offend,
                                                 const int* __restrict__ bin,
                                                 const float* __restrict__ W2,
                                                 const float* __restrict__ b2,
                                                 float* __restrict__ out) {
    __shared__ int lbin[SPANCAP];
    __shared__ float accs[16][HID + 1];
    __shared__ float w2s[HID * OC];
    __shared__ float b2s[OC];
    int t = threadIdx.x;
    for (int i = t; i < HID * OC; i += 256) w2s[i] = W2[i];
    if (t < OC) b2s[t] = b2[t];
    int node0 = blockIdx.x * 16;
    int base0 = offend[node0].x;
    int span = offend[node0 + 15].y - base0;
    if (span <= SPANCAP) {
        for (int i = t; i < span; i += 256) lbin[i] = bin[base0 + i];
    }
    __syncthreads();
    int nl = t >> 4;
    int node = node0 + nl;  // NN = 6250*16 exact
    int lane4 = t & 15;
    int c4 = lane4 & 3, es = lane4 >> 2;
    {
        float di = dis[node];
        int2 oe = offend[node];
        float a[4];
        if (span <= SPANCAP)
            gather_walk(gin, lbin, node, c4, es, oe.x - base0, oe.y - base0, di, a);
        else
            gather_walk(gin, bin, node, c4, es, oe.x, oe.y, di, a);
        if (es == 0) {
#pragma unroll
            for (int k = 0; k < 4; ++k) accs[nl][c4 * 4 + k] = a[k];
        }
    }
    __syncthreads();
    if (lane4 >= 8) return;
    float a[HID];
#pragma unroll
    for (int k = 0; k < HID; ++k) a[k] = accs[nl][k];
    float z[5];
#pragma unroll
    for (int j = 0; j < 5; ++j) {
        int c = lane4 * 5 + j;
        float zz = b2s[c];
#pragma unroll
        for (int k = 0; k < HID; ++k) zz += a[k] * w2s[k * OC + c];
        z[j] = zz;
    }
    float m = z[0];
#pragma unroll
    for (int j = 1; j < 5; ++j) m = fmaxf(m, z[j]);
    m = fmaxf(m, __shfl_xor(m, 1));
    m = fmaxf(m, __shfl_xor(m, 2));
    m = fmaxf(m, __shfl_xor(m, 4));
    float s = 0.f;
#pragma unroll
    for (int j = 0; j < 5; ++j) s += expf(z[j] - m);
    s += __shfl_xor(s, 1);
    s += __shfl_xor(s, 2);
    s += __shfl_xor(s, 4);
    float lse = m + logf(s);
    float* op = out + (size_t)node * OC + lane4 * 5;
#pragma unroll
    for (int j = 0; j < 5; ++j) op[j] = z[j] - lse;
}

extern "C" void kernel_launch(void* const* d_in, const int* in_sizes, int n_in,
                              void* d_out, int out_size, void* d_ws, size_t ws_size,
                              hipStream_t stream) {
    const float* x  = (const float*)d_in[0];
    const int*   ei = (const int*)d_in[1];
    const float* W1 = (const float*)d_in[2];
    const float* b1 = (const float*)d_in[3];
    const float* W2 = (const float*)d_in[4];
    const float* b2 = (const float*)d_in[5];
    float* out = (float*)d_out;

    const int* src = ei;       // edge_index[0]
    const int* dst = ei + NE;  // edge_index[1]

    char* ws = (char*)d_ws;
    size_t o = 0;
    int*      cursor = (int*)(ws + o);      o += (size_t)NBK * CSTRIDE * 4;  // 25KB
    float*    dis    = (float*)(ws + o);    o += (size_t)NN * 4;             // 400KB
    int2*     offend = (int2*)(ws + o);     o += (size_t)NN * 8;             // 800KB
    int*      bin    = (int*)(ws + o);      o += (size_t)NBK * CAP * 4;      // 14.0MB
    unsigned* gbf1   = (unsigned*)(ws + o); o += (size_t)NN * 8 * 4;         // 3.2MB
    unsigned* gbf2   = (unsigned*)(ws + o); o += (size_t)NN * 8 * 4;         // 3.2MB

    dim3 B(256);
    int gC = (NBK * CSTRIDE + 255) / 256;
    int gG = (NN + 15) / 16;  // 6250 blocks

    k_zero_i<<<gC, B, 0, stream>>>(cursor, NBK * CSTRIDE);
    k_part<<<PBLK, 512, 0, stream>>>(src, dst, cursor, bin);
    k_bsort<<<NBK, 512, 0, stream>>>(bin, cursor, offend, dis);
    k_gemm1<<<NN / 16, B, 0, stream>>>(x, W1, dis, gbf1);
    k_gather1<<<gG, B, 0, stream>>>(gbf1, dis, offend, bin, b1, gbf2);
    k_gather2<<<gG, B, 0, stream>>>(gbf2, dis, offend, bin, W2, b2, out);
}